// Round 3
// baseline (238.437 us; speedup 1.0000x reference)
//
#include <hip/hip_runtime.h>
#include <stdint.h>

// SpatialAttention: B=4, C_in=256, C_out=128, N=64*64=4096
// R8: pipe-overlap attack. R7 showed MFMA 30% + VALU 31% + LDS ~34% ~= 95%
// serialized (2-barrier lockstep, all waves same phase; 2x occupancy changed
// nothing). Changes, k_flash only (proj/merge untouched to isolate delta):
// (1) P double-buffer + cross-iteration pipeline: QK(mt) -> PV(mt-1) ->
//     softmax(mt). PV(mt-1) is independent of softmax(mt) -> one basic
//     block, VALU exp/DPP hides under PV MFMA issue. Iter 0 peeled so the
//     hot loop is branch-free through PV+softmax.
// (2) ONE __syncthreads per iter (was 2 barriers + lgkm drain): the single
//     barrier publishes K(mt) AND P(mt-1) and fences every buffer WAR
//     (P[x] write at iter mt vs its readers at mt-1: exactly one barrier
//     between; K dbuf same).
// (3) P tile pitch 72 -> 64 shorts + 3-bit XOR swizzle (col ^ ((row&7)<<3)):
//     pitch-72 af reads were 4-8-way bank-conflicted (conflict counter
//     doubled R5->R7). Uniform bank occupancy on writes and b128 reads.
// (4) s_setprio(1) around PV MFMA cluster (waves now phase-skewed).
// V frags carried in regs one iter (loaded at end of iter mt, used by
// PV(mt) during iter mt+1) -> latency fully covered.

#define B_ 4
#define C_ 256
#define O_ 128
#define N_ 4096

#define AP 72  // proj LDS pitch (bf16 elems)

typedef float v4f __attribute__((ext_vector_type(4)));
typedef short v8s __attribute__((ext_vector_type(8)));
typedef _Float16 v8h __attribute__((ext_vector_type(8)));
typedef uint32_t u32;
typedef unsigned short u16;

__device__ __forceinline__ u16 bf16_rne(float f) {
  u32 u = __builtin_bit_cast(u32, f);
  u += 0x7fffu + ((u >> 16) & 1u);
  return (u16)(u >> 16);
}
__device__ __forceinline__ float bf16_f(u16 s) {
  u32 u = ((u32)s) << 16;
  return __builtin_bit_cast(float, u);
}
__device__ __forceinline__ u16 f16_rne(float f) {
  _Float16 h = (_Float16)f;
  return __builtin_bit_cast(u16, h);
}
__device__ __forceinline__ float f16_f(u16 s) {
  return (float)__builtin_bit_cast(_Float16, s);
}
__device__ __forceinline__ v4f mfma16(v8s a, v8s b, v4f c) {
  return __builtin_amdgcn_mfma_f32_16x16x32_bf16(a, b, c, 0, 0, 0);
}
__device__ __forceinline__ v4f mfma16h(v8h a, v8h b, v4f c) {
  return __builtin_amdgcn_mfma_f32_16x16x32_f16(a, b, c, 0, 0, 0);
}
__device__ __forceinline__ void gl16(const u16* g, u16* l) {
  __builtin_amdgcn_global_load_lds(
      (const __attribute__((address_space(1))) u32*)g,
      (__attribute__((address_space(3))) u32*)l, 16, 0, 0);
}
template <int CTRL>
__device__ __forceinline__ float dppadd(float x) {
  int yi = __builtin_amdgcn_update_dpp(0, __builtin_bit_cast(int, x), CTRL,
                                       0xf, 0xf, true);
  return x + __builtin_bit_cast(float, yi);
}
__device__ __forceinline__ float sum16(float x) {
  x = dppadd<0xB1>(x);   // xor 1
  x = dppadd<0x4E>(x);   // xor 2
  x = dppadd<0x141>(x);  // xor 4 (row_half_mirror)
  x = dppadd<0x140>(x);  // xor 8 (row_mirror)
  return x;
}

// ------------- merged Q/K projection (+V cast on the K instance) ------------
// blocks 0..255: Q = p*Wq+bq -> fp16 hi/lo planes. 256..511: K = b*Wk+bk ->
// fp16 hi plane only, plus bf16 cast of b into Vbf [B][C][N].
// GEMM internals: split-bf16 3-pass (err ~1e-4).
__global__ __launch_bounds__(256) void k_proj(
    const float* __restrict__ Xp, const float* __restrict__ Wq,
    const float* __restrict__ bq, const float* __restrict__ Xb,
    const float* __restrict__ Wk, const float* __restrict__ bk,
    u16* __restrict__ Qh, u16* __restrict__ Ql, u16* __restrict__ Kh,
    u16* __restrict__ Vbf) {
  __shared__ __align__(16) short ah[64 * AP];
  __shared__ __align__(16) short al[64 * AP];
  __shared__ __align__(16) short wh[128 * AP];
  __shared__ __align__(16) short wl[128 * AP];
  const int tid = threadIdx.x;
  const int inst = blockIdx.x >> 8;  // 0 = Q, 1 = K (block-uniform)
  const float* X = inst ? Xb : Xp;
  const float* W = inst ? Wk : Wq;
  const float* bias = inst ? bk : bq;
  const int b = (blockIdx.x >> 6) & 3;
  const int n0 = (blockIdx.x & 63) << 6;
  const int w = tid >> 6, lane = tid & 63, l15 = lane & 15, quad = lane >> 4;
  v4f acc[8];
#pragma unroll
  for (int t = 0; t < 8; t++) acc[t] = (v4f){0.f, 0.f, 0.f, 0.f};

  for (int c0 = 0; c0 < C_; c0 += 64) {
    __syncthreads();
    {  // stage A: transpose X[c][n]->lds[n][c], split hi/lo (+ fused V cast)
      const int c = tid >> 2, nch = (tid & 3) << 4;
      const float* s = X + ((size_t)(b * C_ + c0 + c)) * N_ + n0 + nch;
      float4 f0 = ((const float4*)s)[0], f1 = ((const float4*)s)[1],
             f2 = ((const float4*)s)[2], f3 = ((const float4*)s)[3];
      float v[16] = {f0.x, f0.y, f0.z, f0.w, f1.x, f1.y, f1.z, f1.w,
                     f2.x, f2.y, f2.z, f2.w, f3.x, f3.y, f3.z, f3.w};
      u16 hh[16];
#pragma unroll
      for (int j = 0; j < 16; j++) {
        u16 h = bf16_rne(v[j]);
        u16 l = bf16_rne(v[j] - bf16_f(h));
        hh[j] = h;
        ah[(nch + j) * AP + c] = (short)h;
        al[(nch + j) * AP + c] = (short)l;
      }
      if (inst) {
        u32 pk[8];
#pragma unroll
        for (int jj = 0; jj < 8; jj++)
          pk[jj] = (u32)hh[2 * jj] | ((u32)hh[2 * jj + 1] << 16);
        u16* vd = Vbf + ((size_t)(b * C_ + c0 + c)) * N_ + n0 + nch;
        ((uint4*)vd)[0] = make_uint4(pk[0], pk[1], pk[2], pk[3]);
        ((uint4*)vd)[1] = make_uint4(pk[4], pk[5], pk[6], pk[7]);
      }
    }
    {  // stage W chunk [128 o][64 c], split hi/lo
      const int o = tid >> 1, cch = (tid & 1) << 5;
      const float* s = W + (size_t)o * C_ + c0 + cch;
#pragma unroll
      for (int jj = 0; jj < 8; jj++) {
        float4 f = ((const float4*)s)[jj];
        float v[4] = {f.x, f.y, f.z, f.w};
#pragma unroll
        for (int j = 0; j < 4; j++) {
          u16 h = bf16_rne(v[j]);
          u16 l = bf16_rne(v[j] - bf16_f(h));
          wh[o * AP + cch + jj * 4 + j] = (short)h;
          wl[o * AP + cch + jj * 4 + j] = (short)l;
        }
      }
    }
    __syncthreads();
#pragma unroll
    for (int s = 0; s < 2; s++) {
      v8s a_h = *(const v8s*)&ah[(16 * w + l15) * AP + 32 * s + 8 * quad];
      v8s a_l = *(const v8s*)&al[(16 * w + l15) * AP + 32 * s + 8 * quad];
#pragma unroll
      for (int to = 0; to < 8; to++) {
        v8s b_h = *(const v8s*)&wh[(16 * to + l15) * AP + 32 * s + 8 * quad];
        v8s b_l = *(const v8s*)&wl[(16 * to + l15) * AP + 32 * s + 8 * quad];
        acc[to] = mfma16(a_h, b_h, acc[to]);
        acc[to] = mfma16(a_h, b_l, acc[to]);
        acc[to] = mfma16(a_l, b_h, acc[to]);
      }
    }
  }
#pragma unroll
  for (int to = 0; to < 8; to++) {
    const int o = 16 * to + l15;
    const float bv = bias[o];
#pragma unroll
    for (int r = 0; r < 4; r++) {
      const int n = n0 + 16 * w + 4 * quad + r;  // C/D row = quad*4+reg
      float v = acc[to][r] + bv;
      const size_t idx = (size_t)(b * N_ + n) * O_ + o;
      if (!inst) {
        u16 h = f16_rne(v);
        Qh[idx] = h;
        Ql[idx] = f16_rne(v - f16_f(h));
      } else {
        Kh[idx] = f16_rne(v);
      }
    }
  }
}

// ---------------- fused flash attention (partial over a KV half) ------------
// 8 waves / 512 threads; block = (batch, 64-row Q tile, KV half) decoded so
// XCD x owns the single (b,h)=(x>>1, x&1) stream. 32 iters of 64 tokens.
// QK: wave w owns rows 16*(w&3), tokens 32*(w>>2)+[0,32). PV: wave w owns
// channels 32w..32w+31; P double-buffered in LDS; V straight from global
// into carried B-fragments. Pipeline: QK(mt) -> PV(mt-1) -> softmax(mt).
__global__ __launch_bounds__(512, 4) void k_flash(
    const u16* __restrict__ Qh, const u16* __restrict__ Ql,
    const u16* __restrict__ Khp, const u16* __restrict__ Vbf,
    u16* __restrict__ Opart, float* __restrict__ lpart) {
  // shorts: K dbuf [2][64][128] fp16 @0 (16384),
  //         P dbuf [2][64][64] bf16 XOR-swizzled @16384 (8192).
  // total 24576 shorts = 49152 B -> 2 blocks/CU.
  __shared__ __align__(16) short smem[24576];

  const int tid = threadIdx.x;
  const int w = tid >> 6, lane = tid & 63, l15 = lane & 15, quad = lane >> 4;
  const int wr = w & 3, wh2 = w >> 2;
  const int xcd = blockIdx.x & 7;
  const int b = xcd >> 1, h = xcd & 1;  // XCD owns one (b, half) stream
  const int qt = blockIdx.x >> 3;
  const int n0 = qt << 6;
  const int tok0 = h << 11;
  const int og = (b << 7) + (qt << 1) + h;  // output group (merge layout)

  const u16* khb = Khp + (size_t)b * N_ * O_;
  const u16* vb = Vbf + (size_t)b * C_ * N_;

  // Q fragments (A-layout: row=lane&15, k=32s+8*quad+j), fp16 hi/lo
  v8h qh[4], ql[4];
  {
    const u16* qrh = Qh + (size_t)(b * N_ + n0 + 16 * wr + l15) * O_;
    const u16* qrl = Ql + (size_t)(b * N_ + n0 + 16 * wr + l15) * O_;
#pragma unroll
    for (int s = 0; s < 4; s++) {
      qh[s] = *(const v8h*)(qrh + 32 * s + 8 * quad);
      ql[s] = *(const v8h*)(qrl + 32 * s + 8 * quad);
    }
  }

  v4f oacc[8];  // [rw][cg]: rows 16rw+4quad+r, channels 32w+16cg+l15
#pragma unroll
  for (int t = 0; t < 8; t++) oacc[t] = (v4f){0.f, 0.f, 0.f, 0.f};
  float lstate[4] = {0.f, 0.f, 0.f, 0.f};

  auto stageK = [&](int mtn, int bi) {
    const int m0n = tok0 + (mtn << 6);
    short* kd = smem + bi * 8192;
#pragma unroll
    for (int i = 0; i < 2; i++) {  // 4 rows/issue, 8 rows/wave, 64 rows total
      const int R = 8 * w + 4 * i;
      const int rl = R + (lane >> 4);
      const int cg = (lane & 15) ^ (rl & 15);
      gl16(khb + ((size_t)(m0n + rl) << 7) + (cg << 3), (u16*)(kd + (R << 7)));
    }
  };

  // QK of tile mt from K buffer kc: e[t] rows (wh2*32+16t+l15), 2-pass fp16
  v4f eh[2], el[2];
  auto doQK = [&](const short* kc) {
#pragma unroll
    for (int t = 0; t < 2; t++) {
      eh[t] = (v4f){0.f, 0.f, 0.f, 0.f};
      el[t] = (v4f){0.f, 0.f, 0.f, 0.f};
    }
#pragma unroll
    for (int s = 0; s < 4; s++) {
#pragma unroll
      for (int t = 0; t < 2; t++) {
        const int row = (wh2 << 5) + (t << 4) + l15;
        const int off = (row << 7) + (((4 * s + quad) ^ l15) << 3);
        const v8h kf = *(const v8h*)&kc[off];
        eh[t] = mfma16h(qh[s], kf, eh[t]);
        el[t] = mfma16h(ql[s], kf, el[t]);
      }
    }
  };

  // softmax of current e -> P buffer Pc (XOR-swizzled, pitch 64)
  auto doSM = [&](short* Pc) {
#pragma unroll
    for (int r = 0; r < 4; r++) {
      float p0 = __expf(eh[0][r] + el[0][r]);
      float p1 = __expf(eh[1][r] + el[1][r]);
      lstate[r] += sum16(p0 + p1);
      const int row = (wr << 4) + 4 * quad + r;
      const int sw = (row & 7) << 3;
      const int c0 = (wh2 << 5) + l15;
      Pc[(row << 6) + (c0 ^ sw)] = (short)bf16_rne(p0);
      Pc[(row << 6) + ((c0 + 16) ^ sw)] = (short)bf16_rne(p1);
    }
  };

  // PV over a 64-token tile: af from P buffer Pp, V from carried vfr regs
  v8s vfr[2][2];
  auto doPV = [&](const short* Pp) {
    __builtin_amdgcn_s_setprio(1);
#pragma unroll
    for (int s = 0; s < 2; s++) {
      v8s af[4];
#pragma unroll
      for (int rw = 0; rw < 4; rw++) {
        const int row = (rw << 4) + l15;
        const int col = ((s << 5) + (quad << 3)) ^ ((row & 7) << 3);
        af[rw] = *(const v8s*)&Pp[(row << 6) + col];
      }
#pragma unroll
      for (int cg = 0; cg < 2; cg++)
#pragma unroll
        for (int rw = 0; rw < 4; rw++)
          oacc[rw * 2 + cg] = mfma16(af[rw], vfr[cg][s], oacc[rw * 2 + cg]);
    }
    __builtin_amdgcn_s_setprio(0);
  };

  // V B-frag base: ch row = 32w+l15 (+16 for cg=1), token col 8*quad
  const u16* vrow = vb + (size_t)(32 * w + l15) * N_ + (quad << 3);
  auto loadV = [&](int mtn) {
    const int m0 = tok0 + (mtn << 6);
#pragma unroll
    for (int cg = 0; cg < 2; cg++)
#pragma unroll
      for (int s = 0; s < 2; s++)
        vfr[cg][s] =
            *(const v8s*)(vrow + (size_t)(cg << 4) * N_ + m0 + (s << 5));
  };

  short* const P0 = smem + 16384;
  short* const P1 = smem + 16384 + 4096;

  // ---- peeled iter 0: stage0 -> barrier -> stage1 -> QK(0) -> SM(0) -> V(0)
  stageK(0, 0);
  __syncthreads();  // K(0) landed
  stageK(1, 1);
  doQK(smem);
  doSM(P0);
  loadV(0);

  // ---- main loop mt = 1..31: one barrier per iter, branch-free PV+SM block
#pragma unroll 1
  for (int mt = 1; mt < 32; mt++) {
    const int pr = mt & 1;
    // Single barrier: K(mt) landed+visible (vmcnt0), P(mt-1) visible
    // (lgkm0), and all P[pr]/K[1-pr] readers from iter mt-1 are drained ->
    // safe to overwrite both below.
    __syncthreads();
    if (mt + 1 < 32) stageK(mt + 1, 1 - pr);
    doQK(smem + pr * 8192);     // matrix (+LDS)
    doPV(pr ? P0 : P1);         // matrix, indep of softmax -> overlap
    doSM(pr ? P1 : P0);         // VALU, hides under PV MFMA
    loadV(mt);                  // global, for next iter's PV
  }

  // ---- epilogue: final PV(31) from P[1], then pack + writeback
  __syncthreads();  // P(31) visible to all waves
  doPV(P1);

  // pack bf16 partial O into LDS [256][72] (outx 0..18432 shorts -- disjoint
  // from P[1] @20480, which other waves may still be reading)
  u16* outx = (u16*)smem;
#pragma unroll
  for (int rw = 0; rw < 4; rw++)
#pragma unroll
    for (int cg = 0; cg < 2; cg++) {
      const int ch = (w << 5) + (cg << 4) + l15;
      const v4f o = oacc[rw * 2 + cg];
      u32* q = (u32*)outx;
      const int base = ch * 36 + (rw << 3) + (quad << 1);
      q[base] = (u32)bf16_rne(o[0]) | ((u32)bf16_rne(o[1]) << 16);
      q[base + 1] = (u32)bf16_rne(o[2]) | ((u32)bf16_rne(o[3]) << 16);
    }
  if (l15 == 0) {
#pragma unroll
    for (int r = 0; r < 4; r++)
      lpart[(size_t)og * 128 + (wh2 << 6) + (wr << 4) + 4 * quad + r] =
          lstate[r];
  }
  __syncthreads();
  {
    u16* od = Opart + (size_t)og * 16384;
    const int cr = tid >> 3, col = (tid & 7) << 3;
#pragma unroll
    for (int it = 0; it < 4; it++) {
      const int c = cr + 64 * it;
      *(uint4*)(od + c * 64 + col) = *(const uint4*)&outx[c * 72 + col];
    }
  }
}

// ---------------- merge KV halves: out = (ΣO_i)/(Σl_i) ----------------------
// l has 4 partials per (b,qt,row): 2 halves x 2 token-subwaves.
__global__ __launch_bounds__(256) void k_merge(const u16* __restrict__ Opart,
                                               const float* __restrict__ lpart,
                                               float* __restrict__ out) {
  const int idx = blockIdx.x * 256 + threadIdx.x;
  const int e4 = idx << 2;  // flat out index: b*2^20 + c*2^12 + n
  const int b = e4 >> 20;
  const int c = (e4 >> 12) & 255;
  const int n = e4 & 4095;
  const int qt = n >> 6, row = n & 63;
  const int g2 = (b << 7) + (qt << 1);
  const u16* q0 = Opart + (size_t)g2 * 16384 + c * 64 + row;
  ushort4 a0 = *(const ushort4*)q0;
  ushort4 a1 = *(const ushort4*)(q0 + 16384);
  const float* lb = lpart + (size_t)g2 * 128 + row;
  float4 l0 = *(const float4*)lb;          // h0, subwave0
  float4 l1 = *(const float4*)(lb + 64);   // h0, subwave1
  float4 l2 = *(const float4*)(lb + 128);  // h1, subwave0
  float4 l3 = *(const float4*)(lb + 192);  // h1, subwave1
  float4 o;
  o.x = (bf16_f(a0.x) + bf16_f(a1.x)) / (l0.x + l1.x + l2.x + l3.x);
  o.y = (bf16_f(a0.y) + bf16_f(a1.y)) / (l0.y + l1.y + l2.y + l3.y);
  o.z = (bf16_f(a0.z) + bf16_f(a1.z)) / (l0.z + l1.z + l2.z + l3.z);
  o.w = (bf16_f(a0.w) + bf16_f(a1.w)) / (l0.w + l1.w + l2.w + l3.w);
  *(float4*)(out + e4) = o;
}

extern "C" void kernel_launch(void* const* d_in, const int* in_sizes, int n_in,
                              void* d_out, int out_size, void* d_ws, size_t ws_size,
                              hipStream_t stream) {
  const float* p = (const float*)d_in[0];
  const float* bb = (const float*)d_in[1];
  const float* Wq = (const float*)d_in[2];
  const float* bq = (const float*)d_in[3];
  const float* Wk = (const float*)d_in[4];
  const float* bk = (const float*)d_in[5];
  float* out = (float*)d_out;

  const size_t plane = (size_t)B_ * N_ * O_;  // 2,097,152 u16
  u16* Qh = (u16*)d_ws;
  u16* Ql = Qh + plane;
  u16* Kh = Ql + plane;
  u16* Vbf = Kh + plane;                         // B*C*N u16 = 2 planes
  u16* Opart = Vbf + 2 * plane;                  // 512*16384 u16 = 16.78 MB
  float* lpart = (float*)(Opart + (size_t)512 * 16384);  // 512*128 fp32
  // total ws use ~= 37.8 MB

  hipLaunchKernelGGL(k_proj, dim3(512), dim3(256), 0, stream, p, Wq, bq, bb,
                     Wk, bk, Qh, Ql, Kh, Vbf);
  hipLaunchKernelGGL(k_flash, dim3(B_ * 64 * 2), dim3(512), 0, stream, Qh, Ql,
                     Kh, Vbf, Opart, lpart);
  hipLaunchKernelGGL(k_merge, dim3((B_ * C_ * N_) / (256 * 4)), dim3(256), 0,
                     stream, Opart, lpart, out);
}

// Round 4
// 224.818 us; speedup vs baseline: 1.0606x; 1.0606x over previous
//
#include <hip/hip_runtime.h>
#include <stdint.h>

// SpatialAttention: B=4, C_in=256, C_out=128, N=64*64=4096
// R9: counted-vmcnt schedule (T3/T4) on R7's register shape.
// R8 post-mortem: merged QK->PV->SM block spilled (WRITE_SIZE 19.7->39.2MB
// scratch signature) -> 146us. Its P XOR-swizzle DID work (conflicts 22x
// down). R9 keeps R7's per-iter dataflow (no cross-iter pipeline, no extra
// live state) and removes the structural stall instead:
// (1) K TRIPLE-buffer, stage K(mt+2) each iter. Top-of-iter barrier uses
//     s_waitcnt vmcnt(2) + raw s_barrier -- the K DMA queue is NEVER
//     drained to 0 in the loop (was __syncthreads = vmcnt(0) drain, the
//     m97-ceiling stall). Per-wave FIFO: each wave's K(mt) loads retired
//     by its own pre-PV vmcnt(2) last iter -> barrier only syncs.
// (2) Issue order loadV (4 loads) THEN stageK (2 DMA): compiler's pre-PV
//     vfr wait = vmcnt(2) -> retires V(mt)+K(mt+1), leaves K(mt+2) in
//     flight. K latency cover ~2 iters, V ~0.8 iter.
// (3) P single buffer + XOR swizzle (col ^ ((row&7)<<3), proven in R8).
//     Races: P write(mt+1) vs P read(mt) separated by top barrier; K-buf
//     WAR separated by >=2 barriers; all LDS reads consumed (lgkm-waited)
//     before their wave passes the next barrier.
// (4) sum16/lstate deferred past B2 -> DPP chain hides under PV MFMA;
//     only exp+P-stores precede the lgkm-only B2.
// LDS 57344 B (K 3x16KB + P 8KB) -> 2 blocks/CU; grid 512 = exactly 2/CU.

#define B_ 4
#define C_ 256
#define O_ 128
#define N_ 4096

#define AP 72  // proj LDS pitch (bf16 elems)

typedef float v4f __attribute__((ext_vector_type(4)));
typedef short v8s __attribute__((ext_vector_type(8)));
typedef _Float16 v8h __attribute__((ext_vector_type(8)));
typedef uint32_t u32;
typedef unsigned short u16;

__device__ __forceinline__ u16 bf16_rne(float f) {
  u32 u = __builtin_bit_cast(u32, f);
  u += 0x7fffu + ((u >> 16) & 1u);
  return (u16)(u >> 16);
}
__device__ __forceinline__ float bf16_f(u16 s) {
  u32 u = ((u32)s) << 16;
  return __builtin_bit_cast(float, u);
}
__device__ __forceinline__ u16 f16_rne(float f) {
  _Float16 h = (_Float16)f;
  return __builtin_bit_cast(u16, h);
}
__device__ __forceinline__ float f16_f(u16 s) {
  return (float)__builtin_bit_cast(_Float16, s);
}
__device__ __forceinline__ v4f mfma16(v8s a, v8s b, v4f c) {
  return __builtin_amdgcn_mfma_f32_16x16x32_bf16(a, b, c, 0, 0, 0);
}
__device__ __forceinline__ v4f mfma16h(v8h a, v8h b, v4f c) {
  return __builtin_amdgcn_mfma_f32_16x16x32_f16(a, b, c, 0, 0, 0);
}
__device__ __forceinline__ void gl16(const u16* g, u16* l) {
  __builtin_amdgcn_global_load_lds(
      (const __attribute__((address_space(1))) u32*)g,
      (__attribute__((address_space(3))) u32*)l, 16, 0, 0);
}
template <int CTRL>
__device__ __forceinline__ float dppadd(float x) {
  int yi = __builtin_amdgcn_update_dpp(0, __builtin_bit_cast(int, x), CTRL,
                                       0xf, 0xf, true);
  return x + __builtin_bit_cast(float, yi);
}
__device__ __forceinline__ float sum16(float x) {
  x = dppadd<0xB1>(x);   // xor 1
  x = dppadd<0x4E>(x);   // xor 2
  x = dppadd<0x141>(x);  // xor 4 (row_half_mirror)
  x = dppadd<0x140>(x);  // xor 8 (row_mirror)
  return x;
}

// ------------- merged Q/K projection (+V cast on the K instance) ------------
// blocks 0..255: Q = p*Wq+bq -> fp16 hi/lo planes. 256..511: K = b*Wk+bk ->
// fp16 hi plane only, plus bf16 cast of b into Vbf [B][C][N].
// GEMM internals: split-bf16 3-pass (err ~1e-4).
__global__ __launch_bounds__(256) void k_proj(
    const float* __restrict__ Xp, const float* __restrict__ Wq,
    const float* __restrict__ bq, const float* __restrict__ Xb,
    const float* __restrict__ Wk, const float* __restrict__ bk,
    u16* __restrict__ Qh, u16* __restrict__ Ql, u16* __restrict__ Kh,
    u16* __restrict__ Vbf) {
  __shared__ __align__(16) short ah[64 * AP];
  __shared__ __align__(16) short al[64 * AP];
  __shared__ __align__(16) short wh[128 * AP];
  __shared__ __align__(16) short wl[128 * AP];
  const int tid = threadIdx.x;
  const int inst = blockIdx.x >> 8;  // 0 = Q, 1 = K (block-uniform)
  const float* X = inst ? Xb : Xp;
  const float* W = inst ? Wk : Wq;
  const float* bias = inst ? bk : bq;
  const int b = (blockIdx.x >> 6) & 3;
  const int n0 = (blockIdx.x & 63) << 6;
  const int w = tid >> 6, lane = tid & 63, l15 = lane & 15, quad = lane >> 4;
  v4f acc[8];
#pragma unroll
  for (int t = 0; t < 8; t++) acc[t] = (v4f){0.f, 0.f, 0.f, 0.f};

  for (int c0 = 0; c0 < C_; c0 += 64) {
    __syncthreads();
    {  // stage A: transpose X[c][n]->lds[n][c], split hi/lo (+ fused V cast)
      const int c = tid >> 2, nch = (tid & 3) << 4;
      const float* s = X + ((size_t)(b * C_ + c0 + c)) * N_ + n0 + nch;
      float4 f0 = ((const float4*)s)[0], f1 = ((const float4*)s)[1],
             f2 = ((const float4*)s)[2], f3 = ((const float4*)s)[3];
      float v[16] = {f0.x, f0.y, f0.z, f0.w, f1.x, f1.y, f1.z, f1.w,
                     f2.x, f2.y, f2.z, f2.w, f3.x, f3.y, f3.z, f3.w};
      u16 hh[16];
#pragma unroll
      for (int j = 0; j < 16; j++) {
        u16 h = bf16_rne(v[j]);
        u16 l = bf16_rne(v[j] - bf16_f(h));
        hh[j] = h;
        ah[(nch + j) * AP + c] = (short)h;
        al[(nch + j) * AP + c] = (short)l;
      }
      if (inst) {
        u32 pk[8];
#pragma unroll
        for (int jj = 0; jj < 8; jj++)
          pk[jj] = (u32)hh[2 * jj] | ((u32)hh[2 * jj + 1] << 16);
        u16* vd = Vbf + ((size_t)(b * C_ + c0 + c)) * N_ + n0 + nch;
        ((uint4*)vd)[0] = make_uint4(pk[0], pk[1], pk[2], pk[3]);
        ((uint4*)vd)[1] = make_uint4(pk[4], pk[5], pk[6], pk[7]);
      }
    }
    {  // stage W chunk [128 o][64 c], split hi/lo
      const int o = tid >> 1, cch = (tid & 1) << 5;
      const float* s = W + (size_t)o * C_ + c0 + cch;
#pragma unroll
      for (int jj = 0; jj < 8; jj++) {
        float4 f = ((const float4*)s)[jj];
        float v[4] = {f.x, f.y, f.z, f.w};
#pragma unroll
        for (int j = 0; j < 4; j++) {
          u16 h = bf16_rne(v[j]);
          u16 l = bf16_rne(v[j] - bf16_f(h));
          wh[o * AP + cch + jj * 4 + j] = (short)h;
          wl[o * AP + cch + jj * 4 + j] = (short)l;
        }
      }
    }
    __syncthreads();
#pragma unroll
    for (int s = 0; s < 2; s++) {
      v8s a_h = *(const v8s*)&ah[(16 * w + l15) * AP + 32 * s + 8 * quad];
      v8s a_l = *(const v8s*)&al[(16 * w + l15) * AP + 32 * s + 8 * quad];
#pragma unroll
      for (int to = 0; to < 8; to++) {
        v8s b_h = *(const v8s*)&wh[(16 * to + l15) * AP + 32 * s + 8 * quad];
        v8s b_l = *(const v8s*)&wl[(16 * to + l15) * AP + 32 * s + 8 * quad];
        acc[to] = mfma16(a_h, b_h, acc[to]);
        acc[to] = mfma16(a_h, b_l, acc[to]);
        acc[to] = mfma16(a_l, b_h, acc[to]);
      }
    }
  }
#pragma unroll
  for (int to = 0; to < 8; to++) {
    const int o = 16 * to + l15;
    const float bv = bias[o];
#pragma unroll
    for (int r = 0; r < 4; r++) {
      const int n = n0 + 16 * w + 4 * quad + r;  // C/D row = quad*4+reg
      float v = acc[to][r] + bv;
      const size_t idx = (size_t)(b * N_ + n) * O_ + o;
      if (!inst) {
        u16 h = f16_rne(v);
        Qh[idx] = h;
        Ql[idx] = f16_rne(v - f16_f(h));
      } else {
        Kh[idx] = f16_rne(v);
      }
    }
  }
}

// ---------------- fused flash attention (partial over a KV half) ------------
// 8 waves / 512 threads; block = (batch, 64-row Q tile, KV half) decoded so
// XCD x owns the single (b,h)=(x>>1, x&1) stream. 32 iters of 64 tokens.
// QK: wave w owns rows 16*(w&3), tokens 32*(w>>2)+[0,32). PV: wave w owns
// channels 32w..32w+31; P single-buffered (XOR-swizzled); V straight from
// global into B-fragments. K triple-buffered, counted-vmcnt barriers.
__global__ __launch_bounds__(512, 4) void k_flash(
    const u16* __restrict__ Qh, const u16* __restrict__ Ql,
    const u16* __restrict__ Khp, const u16* __restrict__ Vbf,
    u16* __restrict__ Opart, float* __restrict__ lpart) {
  // shorts: K 3buf [3][64][128] fp16 @0 (24576),
  //         P [64][64] bf16 XOR-swizzled @24576 (4096).
  // total 28672 shorts = 57344 B -> 2 blocks/CU (grid is exactly 2/CU).
  __shared__ __align__(16) short smem[28672];
  short* const Pt = smem + 24576;

  const int tid = threadIdx.x;
  const int w = tid >> 6, lane = tid & 63, l15 = lane & 15, quad = lane >> 4;
  const int wr = w & 3, wh2 = w >> 2;
  const int xcd = blockIdx.x & 7;
  const int b = xcd >> 1, h = xcd & 1;  // XCD owns one (b, half) stream
  const int qt = blockIdx.x >> 3;
  const int n0 = qt << 6;
  const int tok0 = h << 11;
  const int og = (b << 7) + (qt << 1) + h;  // output group (merge layout)

  const u16* khb = Khp + (size_t)b * N_ * O_;
  const u16* vb = Vbf + (size_t)b * C_ * N_;

  // Q fragments (A-layout: row=lane&15, k=32s+8*quad+j), fp16 hi/lo
  v8h qh[4], ql[4];
  {
    const u16* qrh = Qh + (size_t)(b * N_ + n0 + 16 * wr + l15) * O_;
    const u16* qrl = Ql + (size_t)(b * N_ + n0 + 16 * wr + l15) * O_;
#pragma unroll
    for (int s = 0; s < 4; s++) {
      qh[s] = *(const v8h*)(qrh + 32 * s + 8 * quad);
      ql[s] = *(const v8h*)(qrl + 32 * s + 8 * quad);
    }
  }

  v4f oacc[8];  // [rw][cg]: rows 16rw+4quad+r, channels 32w+16cg+l15
#pragma unroll
  for (int t = 0; t < 8; t++) oacc[t] = (v4f){0.f, 0.f, 0.f, 0.f};
  float lstate[4] = {0.f, 0.f, 0.f, 0.f};

  auto stageK = [&](int mtn, int bi) {
    const int m0n = tok0 + (mtn << 6);
    short* kd = smem + bi * 8192;
#pragma unroll
    for (int i = 0; i < 2; i++) {  // 4 rows/issue, 8 rows/wave, 64 rows total
      const int R = 8 * w + 4 * i;
      const int rl = R + (lane >> 4);
      const int cg = (lane & 15) ^ (rl & 15);
      gl16(khb + ((size_t)(m0n + rl) << 7) + (cg << 3), (u16*)(kd + (R << 7)));
    }
  };

  // V B-frag base: ch row = 32w+l15 (+16 for cg=1), token col 8*quad
  v8s vfr[2][2];
  const u16* vrow = vb + (size_t)(32 * w + l15) * N_ + (quad << 3);
  auto loadV = [&](int mtn) {
    const int m0 = tok0 + (mtn << 6);
#pragma unroll
    for (int cg = 0; cg < 2; cg++)
#pragma unroll
      for (int s = 0; s < 2; s++)
        vfr[cg][s] =
            *(const v8s*)(vrow + (size_t)(cg << 4) * N_ + m0 + (s << 5));
  };

  // prologue: K(0) -> buf0, K(1) -> buf1
  stageK(0, 0);
  stageK(1, 1);

  int rb = 0, sb = 2;  // read buf = mt%3, stage buf = (mt+2)%3
#pragma unroll 1
  for (int mt = 0; mt < 32; mt++) {
    // [A] counted barrier: own K(mt) loads retired last iter (pre-PV
    // vmcnt(2)); only K(mt+1) may be outstanding -> vmcnt(2) is a no-op
    // wait, the barrier syncs waves. K DMA queue never drains to 0.
    __builtin_amdgcn_s_waitcnt(0x0F72);  // vmcnt(2) only
    asm volatile("s_barrier" ::: "memory");

    loadV(mt);                            // [B] 4 loads (older than stageK)
    if (mt + 2 < 32) stageK(mt + 2, sb);  // [C] 2 DMA loads (newest)

    // [D] QK: e = (qh+ql) . k, 2-pass fp16
    v4f eh[2], el[2];
#pragma unroll
    for (int t = 0; t < 2; t++) {
      eh[t] = (v4f){0.f, 0.f, 0.f, 0.f};
      el[t] = (v4f){0.f, 0.f, 0.f, 0.f};
    }
    const short* kc = smem + rb * 8192;
#pragma unroll
    for (int s = 0; s < 4; s++) {
#pragma unroll
      for (int t = 0; t < 2; t++) {
        const int row = (wh2 << 5) + (t << 4) + l15;
        const int off = (row << 7) + (((4 * s + quad) ^ l15) << 3);
        const v8h kf = *(const v8h*)&kc[off];
        eh[t] = mfma16h(qh[s], kf, eh[t]);
        el[t] = mfma16h(ql[s], kf, el[t]);
      }
    }

    // [E] exp + P stores (swizzled). Row sums deferred past B2.
    float pp[4];
#pragma unroll
    for (int r = 0; r < 4; r++) {
      float p0 = __expf(eh[0][r] + el[0][r]);
      float p1 = __expf(eh[1][r] + el[1][r]);
      const int row = (wr << 4) + 4 * quad + r;
      const int sw = (row & 7) << 3;
      const int c0 = (wh2 << 5) + l15;
      Pt[(row << 6) + (c0 ^ sw)] = (short)bf16_rne(p0);
      Pt[(row << 6) + ((c0 + 16) ^ sw)] = (short)bf16_rne(p1);
      pp[r] = p0 + p1;
    }
    // [F] B2: P visible (lgkm0) + raw barrier; K DMA stays in flight.
    __builtin_amdgcn_s_waitcnt(0xC07F);  // lgkmcnt(0)
    asm volatile("s_barrier" ::: "memory");

    // [G] PV (compiler waits vmcnt(2) for vfr -> K(mt+2) stays in flight)
    // + deferred DPP row sums overlapping the MFMA issue.
#pragma unroll
    for (int s = 0; s < 2; s++) {
      v8s af[4];
#pragma unroll
      for (int rw = 0; rw < 4; rw++) {
        const int row = (rw << 4) + l15;
        const int col = ((s << 5) + (quad << 3)) ^ ((row & 7) << 3);
        af[rw] = *(const v8s*)&Pt[(row << 6) + col];
      }
#pragma unroll
      for (int cg = 0; cg < 2; cg++)
#pragma unroll
        for (int rw = 0; rw < 4; rw++)
          oacc[rw * 2 + cg] = mfma16(af[rw], vfr[cg][s], oacc[rw * 2 + cg]);
    }
#pragma unroll
    for (int r = 0; r < 4; r++) lstate[r] += sum16(pp[r]);

    rb = (rb == 2) ? 0 : rb + 1;
    sb = (sb == 2) ? 0 : sb + 1;
  }

  // epilogue: pack bf16 partial O into LDS [256][72], write l, copy out
  __syncthreads();  // all loop LDS traffic done; safe to repurpose smem
  u16* outx = (u16*)smem;  // 0..18432 shorts (P @24576 untouched/dead)
#pragma unroll
  for (int rw = 0; rw < 4; rw++)
#pragma unroll
    for (int cg = 0; cg < 2; cg++) {
      const int ch = (w << 5) + (cg << 4) + l15;
      const v4f o = oacc[rw * 2 + cg];
      u32* q = (u32*)outx;
      const int base = ch * 36 + (rw << 3) + (quad << 1);
      q[base] = (u32)bf16_rne(o[0]) | ((u32)bf16_rne(o[1]) << 16);
      q[base + 1] = (u32)bf16_rne(o[2]) | ((u32)bf16_rne(o[3]) << 16);
    }
  if (l15 == 0) {
#pragma unroll
    for (int r = 0; r < 4; r++)
      lpart[(size_t)og * 128 + (wh2 << 6) + (wr << 4) + 4 * quad + r] =
          lstate[r];
  }
  __syncthreads();
  {
    u16* od = Opart + (size_t)og * 16384;
    const int cr = tid >> 3, col = (tid & 7) << 3;
#pragma unroll
    for (int it = 0; it < 4; it++) {
      const int c = cr + 64 * it;
      *(uint4*)(od + c * 64 + col) = *(const uint4*)&outx[c * 72 + col];
    }
  }
}

// ---------------- merge KV halves: out = (ΣO_i)/(Σl_i) ----------------------
// l has 4 partials per (b,qt,row): 2 halves x 2 token-subwaves.
__global__ __launch_bounds__(256) void k_merge(const u16* __restrict__ Opart,
                                               const float* __restrict__ lpart,
                                               float* __restrict__ out) {
  const int idx = blockIdx.x * 256 + threadIdx.x;
  const int e4 = idx << 2;  // flat out index: b*2^20 + c*2^12 + n
  const int b = e4 >> 20;
  const int c = (e4 >> 12) & 255;
  const int n = e4 & 4095;
  const int qt = n >> 6, row = n & 63;
  const int g2 = (b << 7) + (qt << 1);
  const u16* q0 = Opart + (size_t)g2 * 16384 + c * 64 + row;
  ushort4 a0 = *(const ushort4*)q0;
  ushort4 a1 = *(const ushort4*)(q0 + 16384);
  const float* lb = lpart + (size_t)g2 * 128 + row;
  float4 l0 = *(const float4*)lb;          // h0, subwave0
  float4 l1 = *(const float4*)(lb + 64);   // h0, subwave1
  float4 l2 = *(const float4*)(lb + 128);  // h1, subwave0
  float4 l3 = *(const float4*)(lb + 192);  // h1, subwave1
  float4 o;
  o.x = (bf16_f(a0.x) + bf16_f(a1.x)) / (l0.x + l1.x + l2.x + l3.x);
  o.y = (bf16_f(a0.y) + bf16_f(a1.y)) / (l0.y + l1.y + l2.y + l3.y);
  o.z = (bf16_f(a0.z) + bf16_f(a1.z)) / (l0.z + l1.z + l2.z + l3.z);
  o.w = (bf16_f(a0.w) + bf16_f(a1.w)) / (l0.w + l1.w + l2.w + l3.w);
  *(float4*)(out + e4) = o;
}

extern "C" void kernel_launch(void* const* d_in, const int* in_sizes, int n_in,
                              void* d_out, int out_size, void* d_ws, size_t ws_size,
                              hipStream_t stream) {
  const float* p = (const float*)d_in[0];
  const float* bb = (const float*)d_in[1];
  const float* Wq = (const float*)d_in[2];
  const float* bq = (const float*)d_in[3];
  const float* Wk = (const float*)d_in[4];
  const float* bk = (const float*)d_in[5];
  float* out = (float*)d_out;

  const size_t plane = (size_t)B_ * N_ * O_;  // 2,097,152 u16
  u16* Qh = (u16*)d_ws;
  u16* Ql = Qh + plane;
  u16* Kh = Ql + plane;
  u16* Vbf = Kh + plane;                         // B*C*N u16 = 2 planes
  u16* Opart = Vbf + 2 * plane;                  // 512*16384 u16 = 16.78 MB
  float* lpart = (float*)(Opart + (size_t)512 * 16384);  // 512*128 fp32
  // total ws use ~= 37.8 MB

  hipLaunchKernelGGL(k_proj, dim3(512), dim3(256), 0, stream, p, Wq, bq, bb,
                     Wk, bk, Qh, Ql, Kh, Vbf);
  hipLaunchKernelGGL(k_flash, dim3(B_ * 64 * 2), dim3(512), 0, stream, Qh, Ql,
                     Kh, Vbf, Opart, lpart);
  hipLaunchKernelGGL(k_merge, dim3((B_ * C_ * N_) / (256 * 4)), dim3(256), 0,
                     stream, Opart, lpart, out);
}

// Round 5
// 204.406 us; speedup vs baseline: 1.1665x; 1.0999x over previous
//
#include <hip/hip_runtime.h>
#include <stdint.h>

// SpatialAttention: B=4, C_in=256, C_out=128, N=64*64=4096
// R10: single-variable fix of the R7-R9 confound. rocprof showed
// VGPR_Count=64 for every 512-thread k_flash variant: HIP's
// __launch_bounds__ 2nd arg acts as min BLOCKS/CU (CUDA semantics) here --
// (512,4) => 4 blk x 8 waves = 8 waves/SIMD => 64-VGPR cap. Live state
// (~120 regs) never fit -> every variant spilled (R9 WRITE_SIZE 28.9MB vs
// ~17MB real output = ~12MB scratch). Cross-check: (256,2) k_proj => cap
// 256, used 84, no spill.
// Change: __launch_bounds__(512, 2) => cap 128 VGPRs. LDS (57344B) still
// caps at 2 blocks/CU = 4 waves/SIMD, so real occupancy unchanged; we
// stop paying spill for phantom capacity. Everything else = R9:
// K triple-buffer + counted-vmcnt barriers (never drain DMA queue),
// P single buffer XOR-swizzled, V straight to regs, deferred row-sums.

#define B_ 4
#define C_ 256
#define O_ 128
#define N_ 4096

#define AP 72  // proj LDS pitch (bf16 elems)

typedef float v4f __attribute__((ext_vector_type(4)));
typedef short v8s __attribute__((ext_vector_type(8)));
typedef _Float16 v8h __attribute__((ext_vector_type(8)));
typedef uint32_t u32;
typedef unsigned short u16;

__device__ __forceinline__ u16 bf16_rne(float f) {
  u32 u = __builtin_bit_cast(u32, f);
  u += 0x7fffu + ((u >> 16) & 1u);
  return (u16)(u >> 16);
}
__device__ __forceinline__ float bf16_f(u16 s) {
  u32 u = ((u32)s) << 16;
  return __builtin_bit_cast(float, u);
}
__device__ __forceinline__ u16 f16_rne(float f) {
  _Float16 h = (_Float16)f;
  return __builtin_bit_cast(u16, h);
}
__device__ __forceinline__ float f16_f(u16 s) {
  return (float)__builtin_bit_cast(_Float16, s);
}
__device__ __forceinline__ v4f mfma16(v8s a, v8s b, v4f c) {
  return __builtin_amdgcn_mfma_f32_16x16x32_bf16(a, b, c, 0, 0, 0);
}
__device__ __forceinline__ v4f mfma16h(v8h a, v8h b, v4f c) {
  return __builtin_amdgcn_mfma_f32_16x16x32_f16(a, b, c, 0, 0, 0);
}
__device__ __forceinline__ void gl16(const u16* g, u16* l) {
  __builtin_amdgcn_global_load_lds(
      (const __attribute__((address_space(1))) u32*)g,
      (__attribute__((address_space(3))) u32*)l, 16, 0, 0);
}
template <int CTRL>
__device__ __forceinline__ float dppadd(float x) {
  int yi = __builtin_amdgcn_update_dpp(0, __builtin_bit_cast(int, x), CTRL,
                                       0xf, 0xf, true);
  return x + __builtin_bit_cast(float, yi);
}
__device__ __forceinline__ float sum16(float x) {
  x = dppadd<0xB1>(x);   // xor 1
  x = dppadd<0x4E>(x);   // xor 2
  x = dppadd<0x141>(x);  // xor 4 (row_half_mirror)
  x = dppadd<0x140>(x);  // xor 8 (row_mirror)
  return x;
}

// ------------- merged Q/K projection (+V cast on the K instance) ------------
// blocks 0..255: Q = p*Wq+bq -> fp16 hi/lo planes. 256..511: K = b*Wk+bk ->
// fp16 hi plane only, plus bf16 cast of b into Vbf [B][C][N].
// GEMM internals: split-bf16 3-pass (err ~1e-4).
__global__ __launch_bounds__(256) void k_proj(
    const float* __restrict__ Xp, const float* __restrict__ Wq,
    const float* __restrict__ bq, const float* __restrict__ Xb,
    const float* __restrict__ Wk, const float* __restrict__ bk,
    u16* __restrict__ Qh, u16* __restrict__ Ql, u16* __restrict__ Kh,
    u16* __restrict__ Vbf) {
  __shared__ __align__(16) short ah[64 * AP];
  __shared__ __align__(16) short al[64 * AP];
  __shared__ __align__(16) short wh[128 * AP];
  __shared__ __align__(16) short wl[128 * AP];
  const int tid = threadIdx.x;
  const int inst = blockIdx.x >> 8;  // 0 = Q, 1 = K (block-uniform)
  const float* X = inst ? Xb : Xp;
  const float* W = inst ? Wk : Wq;
  const float* bias = inst ? bk : bq;
  const int b = (blockIdx.x >> 6) & 3;
  const int n0 = (blockIdx.x & 63) << 6;
  const int w = tid >> 6, lane = tid & 63, l15 = lane & 15, quad = lane >> 4;
  v4f acc[8];
#pragma unroll
  for (int t = 0; t < 8; t++) acc[t] = (v4f){0.f, 0.f, 0.f, 0.f};

  for (int c0 = 0; c0 < C_; c0 += 64) {
    __syncthreads();
    {  // stage A: transpose X[c][n]->lds[n][c], split hi/lo (+ fused V cast)
      const int c = tid >> 2, nch = (tid & 3) << 4;
      const float* s = X + ((size_t)(b * C_ + c0 + c)) * N_ + n0 + nch;
      float4 f0 = ((const float4*)s)[0], f1 = ((const float4*)s)[1],
             f2 = ((const float4*)s)[2], f3 = ((const float4*)s)[3];
      float v[16] = {f0.x, f0.y, f0.z, f0.w, f1.x, f1.y, f1.z, f1.w,
                     f2.x, f2.y, f2.z, f2.w, f3.x, f3.y, f3.z, f3.w};
      u16 hh[16];
#pragma unroll
      for (int j = 0; j < 16; j++) {
        u16 h = bf16_rne(v[j]);
        u16 l = bf16_rne(v[j] - bf16_f(h));
        hh[j] = h;
        ah[(nch + j) * AP + c] = (short)h;
        al[(nch + j) * AP + c] = (short)l;
      }
      if (inst) {
        u32 pk[8];
#pragma unroll
        for (int jj = 0; jj < 8; jj++)
          pk[jj] = (u32)hh[2 * jj] | ((u32)hh[2 * jj + 1] << 16);
        u16* vd = Vbf + ((size_t)(b * C_ + c0 + c)) * N_ + n0 + nch;
        ((uint4*)vd)[0] = make_uint4(pk[0], pk[1], pk[2], pk[3]);
        ((uint4*)vd)[1] = make_uint4(pk[4], pk[5], pk[6], pk[7]);
      }
    }
    {  // stage W chunk [128 o][64 c], split hi/lo
      const int o = tid >> 1, cch = (tid & 1) << 5;
      const float* s = W + (size_t)o * C_ + c0 + cch;
#pragma unroll
      for (int jj = 0; jj < 8; jj++) {
        float4 f = ((const float4*)s)[jj];
        float v[4] = {f.x, f.y, f.z, f.w};
#pragma unroll
        for (int j = 0; j < 4; j++) {
          u16 h = bf16_rne(v[j]);
          u16 l = bf16_rne(v[j] - bf16_f(h));
          wh[o * AP + cch + jj * 4 + j] = (short)h;
          wl[o * AP + cch + jj * 4 + j] = (short)l;
        }
      }
    }
    __syncthreads();
#pragma unroll
    for (int s = 0; s < 2; s++) {
      v8s a_h = *(const v8s*)&ah[(16 * w + l15) * AP + 32 * s + 8 * quad];
      v8s a_l = *(const v8s*)&al[(16 * w + l15) * AP + 32 * s + 8 * quad];
#pragma unroll
      for (int to = 0; to < 8; to++) {
        v8s b_h = *(const v8s*)&wh[(16 * to + l15) * AP + 32 * s + 8 * quad];
        v8s b_l = *(const v8s*)&wl[(16 * to + l15) * AP + 32 * s + 8 * quad];
        acc[to] = mfma16(a_h, b_h, acc[to]);
        acc[to] = mfma16(a_h, b_l, acc[to]);
        acc[to] = mfma16(a_l, b_h, acc[to]);
      }
    }
  }
#pragma unroll
  for (int to = 0; to < 8; to++) {
    const int o = 16 * to + l15;
    const float bv = bias[o];
#pragma unroll
    for (int r = 0; r < 4; r++) {
      const int n = n0 + 16 * w + 4 * quad + r;  // C/D row = quad*4+reg
      float v = acc[to][r] + bv;
      const size_t idx = (size_t)(b * N_ + n) * O_ + o;
      if (!inst) {
        u16 h = f16_rne(v);
        Qh[idx] = h;
        Ql[idx] = f16_rne(v - f16_f(h));
      } else {
        Kh[idx] = f16_rne(v);
      }
    }
  }
}

// ---------------- fused flash attention (partial over a KV half) ------------
// 8 waves / 512 threads; block = (batch, 64-row Q tile, KV half) decoded so
// XCD x owns the single (b,h)=(x>>1, x&1) stream. 32 iters of 64 tokens.
// QK: wave w owns rows 16*(w&3), tokens 32*(w>>2)+[0,32). PV: wave w owns
// channels 32w..32w+31; P single-buffered (XOR-swizzled); V straight from
// global into B-fragments. K triple-buffered, counted-vmcnt barriers.
// launch_bounds (512,2): 2 blocks/CU floor -> 128-VGPR cap (no spill).
__global__ __launch_bounds__(512, 2) void k_flash(
    const u16* __restrict__ Qh, const u16* __restrict__ Ql,
    const u16* __restrict__ Khp, const u16* __restrict__ Vbf,
    u16* __restrict__ Opart, float* __restrict__ lpart) {
  // shorts: K 3buf [3][64][128] fp16 @0 (24576),
  //         P [64][64] bf16 XOR-swizzled @24576 (4096).
  // total 28672 shorts = 57344 B -> 2 blocks/CU (grid is exactly 2/CU).
  __shared__ __align__(16) short smem[28672];
  short* const Pt = smem + 24576;

  const int tid = threadIdx.x;
  const int w = tid >> 6, lane = tid & 63, l15 = lane & 15, quad = lane >> 4;
  const int wr = w & 3, wh2 = w >> 2;
  const int xcd = blockIdx.x & 7;
  const int b = xcd >> 1, h = xcd & 1;  // XCD owns one (b, half) stream
  const int qt = blockIdx.x >> 3;
  const int n0 = qt << 6;
  const int tok0 = h << 11;
  const int og = (b << 7) + (qt << 1) + h;  // output group (merge layout)

  const u16* khb = Khp + (size_t)b * N_ * O_;
  const u16* vb = Vbf + (size_t)b * C_ * N_;

  // Q fragments (A-layout: row=lane&15, k=32s+8*quad+j), fp16 hi/lo
  v8h qh[4], ql[4];
  {
    const u16* qrh = Qh + (size_t)(b * N_ + n0 + 16 * wr + l15) * O_;
    const u16* qrl = Ql + (size_t)(b * N_ + n0 + 16 * wr + l15) * O_;
#pragma unroll
    for (int s = 0; s < 4; s++) {
      qh[s] = *(const v8h*)(qrh + 32 * s + 8 * quad);
      ql[s] = *(const v8h*)(qrl + 32 * s + 8 * quad);
    }
  }

  v4f oacc[8];  // [rw][cg]: rows 16rw+4quad+r, channels 32w+16cg+l15
#pragma unroll
  for (int t = 0; t < 8; t++) oacc[t] = (v4f){0.f, 0.f, 0.f, 0.f};
  float lstate[4] = {0.f, 0.f, 0.f, 0.f};

  auto stageK = [&](int mtn, int bi) {
    const int m0n = tok0 + (mtn << 6);
    short* kd = smem + bi * 8192;
#pragma unroll
    for (int i = 0; i < 2; i++) {  // 4 rows/issue, 8 rows/wave, 64 rows total
      const int R = 8 * w + 4 * i;
      const int rl = R + (lane >> 4);
      const int cg = (lane & 15) ^ (rl & 15);
      gl16(khb + ((size_t)(m0n + rl) << 7) + (cg << 3), (u16*)(kd + (R << 7)));
    }
  };

  // V B-frag base: ch row = 32w+l15 (+16 for cg=1), token col 8*quad
  v8s vfr[2][2];
  const u16* vrow = vb + (size_t)(32 * w + l15) * N_ + (quad << 3);
  auto loadV = [&](int mtn) {
    const int m0 = tok0 + (mtn << 6);
#pragma unroll
    for (int cg = 0; cg < 2; cg++)
#pragma unroll
      for (int s = 0; s < 2; s++)
        vfr[cg][s] =
            *(const v8s*)(vrow + (size_t)(cg << 4) * N_ + m0 + (s << 5));
  };

  // prologue: K(0) -> buf0, K(1) -> buf1
  stageK(0, 0);
  stageK(1, 1);

  int rb = 0, sb = 2;  // read buf = mt%3, stage buf = (mt+2)%3
#pragma unroll 1
  for (int mt = 0; mt < 32; mt++) {
    // [A] counted barrier: own K(mt) loads retired last iter (pre-PV
    // vmcnt(2)); only K(mt+1) may be outstanding -> vmcnt(2) is a no-op
    // wait, the barrier syncs waves. K DMA queue never drains to 0.
    __builtin_amdgcn_s_waitcnt(0x0F72);  // vmcnt(2) only
    asm volatile("s_barrier" ::: "memory");

    loadV(mt);                            // [B] 4 loads (older than stageK)
    if (mt + 2 < 32) stageK(mt + 2, sb);  // [C] 2 DMA loads (newest)

    // [D] QK: e = (qh+ql) . k, 2-pass fp16
    v4f eh[2], el[2];
#pragma unroll
    for (int t = 0; t < 2; t++) {
      eh[t] = (v4f){0.f, 0.f, 0.f, 0.f};
      el[t] = (v4f){0.f, 0.f, 0.f, 0.f};
    }
    const short* kc = smem + rb * 8192;
#pragma unroll
    for (int s = 0; s < 4; s++) {
#pragma unroll
      for (int t = 0; t < 2; t++) {
        const int row = (wh2 << 5) + (t << 4) + l15;
        const int off = (row << 7) + (((4 * s + quad) ^ l15) << 3);
        const v8h kf = *(const v8h*)&kc[off];
        eh[t] = mfma16h(qh[s], kf, eh[t]);
        el[t] = mfma16h(ql[s], kf, el[t]);
      }
    }

    // [E] exp + P stores (swizzled). Row sums deferred past B2.
    float pp[4];
#pragma unroll
    for (int r = 0; r < 4; r++) {
      float p0 = __expf(eh[0][r] + el[0][r]);
      float p1 = __expf(eh[1][r] + el[1][r]);
      const int row = (wr << 4) + 4 * quad + r;
      const int sw = (row & 7) << 3;
      const int c0 = (wh2 << 5) + l15;
      Pt[(row << 6) + (c0 ^ sw)] = (short)bf16_rne(p0);
      Pt[(row << 6) + ((c0 + 16) ^ sw)] = (short)bf16_rne(p1);
      pp[r] = p0 + p1;
    }
    // [F] B2: P visible (lgkm0) + raw barrier; K DMA stays in flight.
    __builtin_amdgcn_s_waitcnt(0xC07F);  // lgkmcnt(0)
    asm volatile("s_barrier" ::: "memory");

    // [G] PV (compiler waits vmcnt(2) for vfr -> K(mt+2) stays in flight)
    // + deferred DPP row sums overlapping the MFMA issue.
#pragma unroll
    for (int s = 0; s < 2; s++) {
      v8s af[4];
#pragma unroll
      for (int rw = 0; rw < 4; rw++) {
        const int row = (rw << 4) + l15;
        const int col = ((s << 5) + (quad << 3)) ^ ((row & 7) << 3);
        af[rw] = *(const v8s*)&Pt[(row << 6) + col];
      }
#pragma unroll
      for (int cg = 0; cg < 2; cg++)
#pragma unroll
        for (int rw = 0; rw < 4; rw++)
          oacc[rw * 2 + cg] = mfma16(af[rw], vfr[cg][s], oacc[rw * 2 + cg]);
    }
#pragma unroll
    for (int r = 0; r < 4; r++) lstate[r] += sum16(pp[r]);

    rb = (rb == 2) ? 0 : rb + 1;
    sb = (sb == 2) ? 0 : sb + 1;
  }

  // epilogue: pack bf16 partial O into LDS [256][72], write l, copy out
  __syncthreads();  // all loop LDS traffic done; safe to repurpose smem
  u16* outx = (u16*)smem;  // 0..18432 shorts (P @24576 untouched/dead)
#pragma unroll
  for (int rw = 0; rw < 4; rw++)
#pragma unroll
    for (int cg = 0; cg < 2; cg++) {
      const int ch = (w << 5) + (cg << 4) + l15;
      const v4f o = oacc[rw * 2 + cg];
      u32* q = (u32*)outx;
      const int base = ch * 36 + (rw << 3) + (quad << 1);
      q[base] = (u32)bf16_rne(o[0]) | ((u32)bf16_rne(o[1]) << 16);
      q[base + 1] = (u32)bf16_rne(o[2]) | ((u32)bf16_rne(o[3]) << 16);
    }
  if (l15 == 0) {
#pragma unroll
    for (int r = 0; r < 4; r++)
      lpart[(size_t)og * 128 + (wh2 << 6) + (wr << 4) + 4 * quad + r] =
          lstate[r];
  }
  __syncthreads();
  {
    u16* od = Opart + (size_t)og * 16384;
    const int cr = tid >> 3, col = (tid & 7) << 3;
#pragma unroll
    for (int it = 0; it < 4; it++) {
      const int c = cr + 64 * it;
      *(uint4*)(od + c * 64 + col) = *(const uint4*)&outx[c * 72 + col];
    }
  }
}

// ---------------- merge KV halves: out = (ΣO_i)/(Σl_i) ----------------------
// l has 4 partials per (b,qt,row): 2 halves x 2 token-subwaves.
__global__ __launch_bounds__(256) void k_merge(const u16* __restrict__ Opart,
                                               const float* __restrict__ lpart,
                                               float* __restrict__ out) {
  const int idx = blockIdx.x * 256 + threadIdx.x;
  const int e4 = idx << 2;  // flat out index: b*2^20 + c*2^12 + n
  const int b = e4 >> 20;
  const int c = (e4 >> 12) & 255;
  const int n = e4 & 4095;
  const int qt = n >> 6, row = n & 63;
  const int g2 = (b << 7) + (qt << 1);
  const u16* q0 = Opart + (size_t)g2 * 16384 + c * 64 + row;
  ushort4 a0 = *(const ushort4*)q0;
  ushort4 a1 = *(const ushort4*)(q0 + 16384);
  const float* lb = lpart + (size_t)g2 * 128 + row;
  float4 l0 = *(const float4*)lb;          // h0, subwave0
  float4 l1 = *(const float4*)(lb + 64);   // h0, subwave1
  float4 l2 = *(const float4*)(lb + 128);  // h1, subwave0
  float4 l3 = *(const float4*)(lb + 192);  // h1, subwave1
  float4 o;
  o.x = (bf16_f(a0.x) + bf16_f(a1.x)) / (l0.x + l1.x + l2.x + l3.x);
  o.y = (bf16_f(a0.y) + bf16_f(a1.y)) / (l0.y + l1.y + l2.y + l3.y);
  o.z = (bf16_f(a0.z) + bf16_f(a1.z)) / (l0.z + l1.z + l2.z + l3.z);
  o.w = (bf16_f(a0.w) + bf16_f(a1.w)) / (l0.w + l1.w + l2.w + l3.w);
  *(float4*)(out + e4) = o;
}

extern "C" void kernel_launch(void* const* d_in, const int* in_sizes, int n_in,
                              void* d_out, int out_size, void* d_ws, size_t ws_size,
                              hipStream_t stream) {
  const float* p = (const float*)d_in[0];
  const float* bb = (const float*)d_in[1];
  const float* Wq = (const float*)d_in[2];
  const float* bq = (const float*)d_in[3];
  const float* Wk = (const float*)d_in[4];
  const float* bk = (const float*)d_in[5];
  float* out = (float*)d_out;

  const size_t plane = (size_t)B_ * N_ * O_;  // 2,097,152 u16
  u16* Qh = (u16*)d_ws;
  u16* Ql = Qh + plane;
  u16* Kh = Ql + plane;
  u16* Vbf = Kh + plane;                         // B*C*N u16 = 2 planes
  u16* Opart = Vbf + 2 * plane;                  // 512*16384 u16 = 16.78 MB
  float* lpart = (float*)(Opart + (size_t)512 * 16384);  // 512*128 fp32
  // total ws use ~= 37.8 MB

  hipLaunchKernelGGL(k_proj, dim3(512), dim3(256), 0, stream, p, Wq, bq, bb,
                     Wk, bk, Qh, Ql, Kh, Vbf);
  hipLaunchKernelGGL(k_flash, dim3(B_ * 64 * 2), dim3(512), 0, stream, Qh, Ql,
                     Kh, Vbf, Opart, lpart);
  hipLaunchKernelGGL(k_merge, dim3((B_ * C_ * N_) / (256 * 4)), dim3(256), 0,
                     stream, Opart, lpart, out);
}

// Round 6
// 177.533 us; speedup vs baseline: 1.3431x; 1.1514x over previous
//
#include <hip/hip_runtime.h>
#include <stdint.h>

// SpatialAttention: B=4, C_in=256, C_out=128, H=W=64 (N=4096)
// R11: revert to the proven R5 structure (96.9us k_flash) and delete work.
// R6-R10 post-mortems: KV-quarters broke streaming synchrony (270us);
// 8-wave restructure was neutral; counted-vmcnt/3-buffer schedules were
// net-negative even after the launch_bounds VGPR-cap confound (R10: VGPR
// 72, zero spill, still 111us vs R5's 96.9). Conclusion: R5's simple
// 2-barrier 4-wave loop is the best schedule found; change the WORK.
// Change vs R5 (single edit): Q projected to ONE fp16 plane (drop Ql).
// QK becomes 1-pass: 8 MFMA/iter/wave instead of 16 (-25% of k_flash
// MFMA), -8 fp32 adds on the softmax-critical path, -2MB fetch, -1 plane
// in proj. Error symmetry: K is ALREADY single fp16 (R5's own change,
// absmax unchanged) -- Q-lo contributes the same ~2e-3 energy jitter as
// the K-lo term that was dropped, below the bf16-P quantization already
// present. Everything else byte-identical to R5.

#define B_ 4
#define C_ 256
#define O_ 128
#define N_ 4096

#define AP 72  // proj LDS pitch (bf16 elems)
#define PP 40  // flash P-tile pitch (32 cols + pad)

typedef float v4f __attribute__((ext_vector_type(4)));
typedef short v8s __attribute__((ext_vector_type(8)));
typedef _Float16 v8h __attribute__((ext_vector_type(8)));
typedef uint32_t u32;
typedef unsigned short u16;

__device__ __forceinline__ u16 bf16_rne(float f) {
  u32 u = __builtin_bit_cast(u32, f);
  u += 0x7fffu + ((u >> 16) & 1u);
  return (u16)(u >> 16);
}
__device__ __forceinline__ float bf16_f(u16 s) {
  u32 u = ((u32)s) << 16;
  return __builtin_bit_cast(float, u);
}
__device__ __forceinline__ u16 f16_rne(float f) {
  _Float16 h = (_Float16)f;
  return __builtin_bit_cast(u16, h);
}
__device__ __forceinline__ float f16_f(u16 s) {
  return (float)__builtin_bit_cast(_Float16, s);
}
__device__ __forceinline__ v4f mfma16(v8s a, v8s b, v4f c) {
  return __builtin_amdgcn_mfma_f32_16x16x32_bf16(a, b, c, 0, 0, 0);
}
__device__ __forceinline__ v4f mfma16h(v8h a, v8h b, v4f c) {
  return __builtin_amdgcn_mfma_f32_16x16x32_f16(a, b, c, 0, 0, 0);
}
__device__ __forceinline__ void gl16(const u16* g, u16* l) {
  __builtin_amdgcn_global_load_lds(
      (const __attribute__((address_space(1))) u32*)g,
      (__attribute__((address_space(3))) u32*)l, 16, 0, 0);
}
template <int CTRL>
__device__ __forceinline__ float dppadd(float x) {
  int yi = __builtin_amdgcn_update_dpp(0, __builtin_bit_cast(int, x), CTRL,
                                       0xf, 0xf, true);
  return x + __builtin_bit_cast(float, yi);
}
__device__ __forceinline__ float sum16(float x) {
  x = dppadd<0xB1>(x);   // xor 1
  x = dppadd<0x4E>(x);   // xor 2
  x = dppadd<0x141>(x);  // xor 4 (row_half_mirror)
  x = dppadd<0x140>(x);  // xor 8 (row_mirror)
  return x;
}

// ------------- merged Q/K projection (+V cast on the K instance) ------------
// blocks 0..255: Q = p*Wq+bq -> single fp16 plane. 256..511: K = b*Wk+bk ->
// fp16 plane, plus bf16 cast of b into Vbf [B][C][N].
// GEMM internals: split-bf16 3-pass (err ~1e-4).
__global__ __launch_bounds__(256) void k_proj(
    const float* __restrict__ Xp, const float* __restrict__ Wq,
    const float* __restrict__ bq, const float* __restrict__ Xb,
    const float* __restrict__ Wk, const float* __restrict__ bk,
    u16* __restrict__ Qh, u16* __restrict__ Kh, u16* __restrict__ Vbf) {
  __shared__ __align__(16) short ah[64 * AP];
  __shared__ __align__(16) short al[64 * AP];
  __shared__ __align__(16) short wh[128 * AP];
  __shared__ __align__(16) short wl[128 * AP];
  const int tid = threadIdx.x;
  const int inst = blockIdx.x >> 8;  // 0 = Q, 1 = K (block-uniform)
  const float* X = inst ? Xb : Xp;
  const float* W = inst ? Wk : Wq;
  const float* bias = inst ? bk : bq;
  const int b = (blockIdx.x >> 6) & 3;
  const int n0 = (blockIdx.x & 63) << 6;
  const int w = tid >> 6, lane = tid & 63, l15 = lane & 15, quad = lane >> 4;
  v4f acc[8];
#pragma unroll
  for (int t = 0; t < 8; t++) acc[t] = (v4f){0.f, 0.f, 0.f, 0.f};

  for (int c0 = 0; c0 < C_; c0 += 64) {
    __syncthreads();
    {  // stage A: transpose X[c][n]->lds[n][c], split hi/lo (+ fused V cast)
      const int c = tid >> 2, nch = (tid & 3) << 4;
      const float* s = X + ((size_t)(b * C_ + c0 + c)) * N_ + n0 + nch;
      float4 f0 = ((const float4*)s)[0], f1 = ((const float4*)s)[1],
             f2 = ((const float4*)s)[2], f3 = ((const float4*)s)[3];
      float v[16] = {f0.x, f0.y, f0.z, f0.w, f1.x, f1.y, f1.z, f1.w,
                     f2.x, f2.y, f2.z, f2.w, f3.x, f3.y, f3.z, f3.w};
      u16 hh[16];
#pragma unroll
      for (int j = 0; j < 16; j++) {
        u16 h = bf16_rne(v[j]);
        u16 l = bf16_rne(v[j] - bf16_f(h));
        hh[j] = h;
        ah[(nch + j) * AP + c] = (short)h;
        al[(nch + j) * AP + c] = (short)l;
      }
      if (inst) {
        u32 pk[8];
#pragma unroll
        for (int jj = 0; jj < 8; jj++)
          pk[jj] = (u32)hh[2 * jj] | ((u32)hh[2 * jj + 1] << 16);
        u16* vd = Vbf + ((size_t)(b * C_ + c0 + c)) * N_ + n0 + nch;
        ((uint4*)vd)[0] = make_uint4(pk[0], pk[1], pk[2], pk[3]);
        ((uint4*)vd)[1] = make_uint4(pk[4], pk[5], pk[6], pk[7]);
      }
    }
    {  // stage W chunk [128 o][64 c], split hi/lo
      const int o = tid >> 1, cch = (tid & 1) << 5;
      const float* s = W + (size_t)o * C_ + c0 + cch;
#pragma unroll
      for (int jj = 0; jj < 8; jj++) {
        float4 f = ((const float4*)s)[jj];
        float v[4] = {f.x, f.y, f.z, f.w};
#pragma unroll
        for (int j = 0; j < 4; j++) {
          u16 h = bf16_rne(v[j]);
          u16 l = bf16_rne(v[j] - bf16_f(h));
          wh[o * AP + cch + jj * 4 + j] = (short)h;
          wl[o * AP + cch + jj * 4 + j] = (short)l;
        }
      }
    }
    __syncthreads();
#pragma unroll
    for (int s = 0; s < 2; s++) {
      v8s a_h = *(const v8s*)&ah[(16 * w + l15) * AP + 32 * s + 8 * quad];
      v8s a_l = *(const v8s*)&al[(16 * w + l15) * AP + 32 * s + 8 * quad];
#pragma unroll
      for (int to = 0; to < 8; to++) {
        v8s b_h = *(const v8s*)&wh[(16 * to + l15) * AP + 32 * s + 8 * quad];
        v8s b_l = *(const v8s*)&wl[(16 * to + l15) * AP + 32 * s + 8 * quad];
        acc[to] = mfma16(a_h, b_h, acc[to]);
        acc[to] = mfma16(a_h, b_l, acc[to]);
        acc[to] = mfma16(a_l, b_h, acc[to]);
      }
    }
  }
#pragma unroll
  for (int to = 0; to < 8; to++) {
    const int o = 16 * to + l15;
    const float bv = bias[o];
    u16* dst = inst ? Kh : Qh;
#pragma unroll
    for (int r = 0; r < 4; r++) {
      const int n = n0 + 16 * w + 4 * quad + r;  // C/D row = quad*4+reg
      float v = acc[to][r] + bv;
      const size_t idx = (size_t)(b * N_ + n) * O_ + o;
      dst[idx] = f16_rne(v);
    }
  }
}

// ---------------- fused flash attention (partial over a KV half) ------------
// block = (batch, 64-row Q tile, KV half); 4 waves. QK: wave w owns Q rows
// 16w..16w+15 (1-pass fp16). PV: wave w owns channels 64w..64w+63 for all 64
// rows; P crosses waves via LDS + raw s_barrier (lgkm wait only).
__global__ __launch_bounds__(256, 2) void k_flash(
    const u16* __restrict__ Qh, const u16* __restrict__ Khp,
    const u16* __restrict__ Vbf, u16* __restrict__ Opart,
    float* __restrict__ lpart) {
  // shorts: buf i at i*12288: K [32][128] fp16 @0, V [256][32] bf16 @4096
  //         P [64][PP] @24576 (2560 shorts)
  __shared__ __align__(16) short smem[27136];  // 54272 B -> 2 blocks/CU
  short* Pt = smem + 24576;

  const int tid = threadIdx.x;
  const int w = tid >> 6, lane = tid & 63, l15 = lane & 15, quad = lane >> 4;
  const int h = blockIdx.x & 1;
  const int qt = (blockIdx.x >> 1) & 63;
  const int b = blockIdx.x >> 7;
  const int n0 = qt << 6;
  const int tok0 = h << 11;

  const u16* khb = Khp + (size_t)b * N_ * O_;
  const u16* vb = Vbf + (size_t)b * C_ * N_;

  // Q fragments (A-layout: row=lane&15, k=32s+8*quad+j), single fp16
  v8h qh[4];
  {
    const u16* qrh = Qh + (size_t)(b * N_ + n0 + 16 * w + l15) * O_;
#pragma unroll
    for (int s = 0; s < 4; s++) {
      qh[s] = *(const v8h*)(qrh + 32 * s + 8 * quad);
    }
  }

  v4f oacc[16];  // [rw][cg]: rows 16rw+4quad+r, channels 64w+16cg+l15
#pragma unroll
  for (int t = 0; t < 16; t++) oacc[t] = (v4f){0.f, 0.f, 0.f, 0.f};
  float lstate[4] = {0.f, 0.f, 0.f, 0.f};

  auto stage = [&](int mtn, int bi) {
    const int m0n = tok0 + (mtn << 5);
    short* kd = smem + bi * 12288;
    short* vd = kd + 4096;
#pragma unroll
    for (int i = 0; i < 2; i++) {  // K fp16: 4 rows/issue, 8 rows/wave
      const int R = 8 * w + 4 * i;
      const int rl = R + (lane >> 4);
      const int cg = (lane & 15) ^ (rl & 15);
      gl16(khb + ((size_t)(m0n + rl) << 7) + (cg << 3), (u16*)(kd + (R << 7)));
    }
#pragma unroll
    for (int i = 0; i < 4; i++) {  // V bf16: 16 chan-rows/issue, 64/wave
      const int R = 64 * w + 16 * i;
      const int rl = R + (lane >> 2);
      const int cg = (lane & 3) ^ ((rl >> 1) & 3);
      gl16(vb + (size_t)rl * N_ + m0n + (cg << 3), (u16*)(vd + (R << 5)));
    }
  };

  stage(0, 0);

#pragma unroll 1
  for (int mt = 0; mt < 64; mt++) {
    const int pr = mt & 1;
    __syncthreads();  // B1: drains vmcnt(0) -> tile mt staged + visible
    if (mt + 1 < 64) stage(mt + 1, 1 - pr);
    const short* kc = smem + pr * 12288;
    const short* vc = kc + 4096;

    // QK: e = qh . k, 1-pass fp16, two acc chains for ILP
    v4f eh[2];
#pragma unroll
    for (int t = 0; t < 2; t++) {
      eh[t] = (v4f){0.f, 0.f, 0.f, 0.f};
    }
#pragma unroll
    for (int s = 0; s < 4; s++) {
#pragma unroll
      for (int t = 0; t < 2; t++) {
        const int off = ((16 * t + l15) << 7) + (((4 * s + quad) ^ l15) << 3);
        const v8h kf = *(const v8h*)&kc[off];
        eh[t] = mfma16h(qh[s], kf, eh[t]);
      }
    }

    // no-max softmax: p=exp(e); DPP 16-lane row sums; write P tile (shared)
#pragma unroll
    for (int r = 0; r < 4; r++) {
      float p0 = __expf(eh[0][r]);
      float p1 = __expf(eh[1][r]);
      lstate[r] += sum16(p0 + p1);
      Pt[(16 * w + 4 * quad + r) * PP + l15] = (short)bf16_rne(p0);
      Pt[(16 * w + 4 * quad + r) * PP + 16 + l15] = (short)bf16_rne(p1);
    }
    // B2: P handoff across waves. lgkm-only wait + raw barrier so the
    // staged prefetch (vmcnt queue) is NOT drained mid-iter.
    __builtin_amdgcn_s_waitcnt(0xC07F);  // lgkmcnt(0)
    asm volatile("s_barrier" ::: "memory");

    // PV channel-split: oacc[rw][cg] += P(rows 16rw) * V(ch 64w+16cg)
    v8s af[4];
#pragma unroll
    for (int rw = 0; rw < 4; rw++)
      af[rw] = *(const v8s*)&Pt[(16 * rw + l15) * PP + 8 * quad];
#pragma unroll
    for (int cg = 0; cg < 4; cg++) {
      const int ch = 64 * w + 16 * cg + l15;
      const int voff = (ch << 5) + ((quad ^ ((ch >> 1) & 3)) << 3);
      const v8s vf = *(const v8s*)&vc[voff];
#pragma unroll
      for (int rw = 0; rw < 4; rw++)
        oacc[rw * 4 + cg] = mfma16(af[rw], vf, oacc[rw * 4 + cg]);
    }
  }

  // epilogue: pack bf16 partial O into LDS [256][72], write l, copy out
  __syncthreads();
  u16* outx = (u16*)smem;  // pitch 72 shorts (144 B, 16B-aligned rows)
#pragma unroll
  for (int rw = 0; rw < 4; rw++)
#pragma unroll
    for (int cg = 0; cg < 4; cg++) {
      const int ch = 64 * w + 16 * cg + l15;
      const v4f o = oacc[rw * 4 + cg];
      u32* q = (u32*)outx;
      const int base = ch * 36 + 8 * rw + 2 * quad;
      q[base] = (u32)bf16_rne(o[0]) | ((u32)bf16_rne(o[1]) << 16);
      q[base + 1] = (u32)bf16_rne(o[2]) | ((u32)bf16_rne(o[3]) << 16);
    }
  if (l15 == 0) {
#pragma unroll
    for (int r = 0; r < 4; r++)
      lpart[(size_t)blockIdx.x * 64 + 16 * w + 4 * quad + r] = lstate[r];
  }
  __syncthreads();
  {
    u16* od = Opart + (size_t)blockIdx.x * 16384;
    const int cr = tid >> 2, nch = (tid & 3) << 4;
#pragma unroll
    for (int it = 0; it < 4; it++) {
      const int c = cr + 64 * it;
      const u16* srcr = &outx[c * 72 + nch];
      uint4* dst = (uint4*)(od + c * 64 + nch);
      dst[0] = ((const uint4*)srcr)[0];
      dst[1] = ((const uint4*)srcr)[1];
    }
  }
}

// ---------------- merge KV halves: out = (O0+O1)/(l0+l1) --------------------
__global__ __launch_bounds__(256) void k_merge(const u16* __restrict__ Opart,
                                               const float* __restrict__ lpart,
                                               float* __restrict__ out) {
  const int idx = blockIdx.x * 256 + threadIdx.x;
  const int e4 = idx << 2;  // flat out index: b*2^20 + c*2^12 + n
  const int b = e4 >> 20;
  const int c = (e4 >> 12) & 255;
  const int n = e4 & 4095;
  const int qt = n >> 6, row = n & 63;
  const int g = (b * 64 + qt) * 2;
  const u16* q0 = Opart + (size_t)g * 16384 + c * 64 + row;
  ushort4 a0 = *(const ushort4*)q0;
  ushort4 a1 = *(const ushort4*)(q0 + 16384);
  float4 l0 = *(const float4*)(lpart + (size_t)g * 64 + row);
  float4 l1 = *(const float4*)(lpart + (size_t)g * 64 + 64 + row);
  float4 o;
  o.x = (bf16_f(a0.x) + bf16_f(a1.x)) / (l0.x + l1.x);
  o.y = (bf16_f(a0.y) + bf16_f(a1.y)) / (l0.y + l1.y);
  o.z = (bf16_f(a0.z) + bf16_f(a1.z)) / (l0.z + l1.z);
  o.w = (bf16_f(a0.w) + bf16_f(a1.w)) / (l0.w + l1.w);
  *(float4*)(out + e4) = o;
}

extern "C" void kernel_launch(void* const* d_in, const int* in_sizes, int n_in,
                              void* d_out, int out_size, void* d_ws, size_t ws_size,
                              hipStream_t stream) {
  const float* p = (const float*)d_in[0];
  const float* bb = (const float*)d_in[1];
  const float* Wq = (const float*)d_in[2];
  const float* bq = (const float*)d_in[3];
  const float* Wk = (const float*)d_in[4];
  const float* bk = (const float*)d_in[5];
  float* out = (float*)d_out;

  const size_t plane = (size_t)B_ * N_ * O_;  // 2,097,152 u16
  u16* Qh = (u16*)d_ws;
  u16* Kh = Qh + plane;
  u16* Vbf = Kh + plane;                         // B*C*N u16 = 2 planes
  u16* Opart = Vbf + 2 * plane;                  // 512*16384 u16 = 16.78 MB
  float* lpart = (float*)(Opart + (size_t)512 * 16384);  // 512*64 fp32
  // total ws use ~= 33.4 MB

  hipLaunchKernelGGL(k_proj, dim3(512), dim3(256), 0, stream, p, Wq, bq, bb,
                     Wk, bk, Qh, Kh, Vbf);
  hipLaunchKernelGGL(k_flash, dim3(B_ * 64 * 2), dim3(256), 0, stream, Qh, Kh,
                     Vbf, Opart, lpart);
  hipLaunchKernelGGL(k_merge, dim3((B_ * C_ * N_) / (256 * 4)), dim3(256), 0,
                     stream, Opart, lpart, out);
}